// Round 2
// baseline (874.194 us; speedup 1.0000x reference)
//
#include <hip/hip_runtime.h>
#include <math.h>

// ---------------------------------------------------------------------------
// R-GCN (basis decomposition, B=2), 2 layers.
//   Layer: hb[n,b,:] = h[n,:] @ basis[b]          (dense, grid.y = 1,2)
//          agg[n,:]  = h[n,:] @ loop_w + bias     (dense, grid.y = 0)
//          agg[dst]  += sum_b comp[et,b]*hb[src,b,:]   (edge, atomics)
//          h' = act(agg)
//
// Dense kernel: W column-major in LDS with float4 XOR swizzle
// (element (j,d4) at j*KF4 + (d4 ^ (j&7))) -> conflict-free ds_read_b128.
// 8 nodes per wave: 32 FMA per LDS read -> VALU-bound.
// ---------------------------------------------------------------------------

template<int K>
__global__ __launch_bounds__(256) void rgcn_dense(
    const float* __restrict__ x,      // [nNodes][K]
    const float* __restrict__ loopw,  // [K][64]
    const float* __restrict__ basis,  // [2][K][64]
    const float* __restrict__ bias,   // [64]
    float* __restrict__ agg,          // [nNodes][64]   (g==0 writes here)
    float* __restrict__ hb,           // [nNodes][2][64] (g==1,2 write here)
    int nNodes)
{
    constexpr int KF4 = K / 4;
    __shared__ float4 WT[64 * KF4];   // swizzled, no pad needed
    const int g = blockIdx.y;
    const float* __restrict__ W =
        (g == 0) ? loopw : (basis + (size_t)(g - 1) * K * 64);

    // stage W transposed + swizzled: coalesced global reads
    for (int idx = threadIdx.x; idx < K * 64; idx += 256) {
        const int d = idx >> 6, j = idx & 63;
        const int d4 = d >> 2, w = d & 3;
        reinterpret_cast<float*>(&WT[j * KF4 + (d4 ^ (j & 7))])[w] = W[idx];
    }
    __syncthreads();

    const int lane = threadIdx.x & 63;
    const int wid  = threadIdx.x >> 6;
    const int jx   = lane & 7;
    const float4* __restrict__ wrow = &WT[lane * KF4];
    const float bj = (g == 0) ? bias[lane] : 0.0f;

    const int nTiles = (nNodes + 7) >> 3;
    const int waveStride = gridDim.x * 4;

    for (int tile = blockIdx.x * 4 + wid; tile < nTiles; tile += waveStride) {
        const int n0 = tile * 8;
        if (n0 + 8 <= nNodes) {
            const float4* __restrict__ xp =
                reinterpret_cast<const float4*>(x + (size_t)n0 * K);
            float acc[8] = {0.f, 0.f, 0.f, 0.f, 0.f, 0.f, 0.f, 0.f};
            #pragma unroll 4
            for (int d4 = 0; d4 < KF4; ++d4) {
                const float4 wv = wrow[d4 ^ jx];
                #pragma unroll
                for (int n = 0; n < 8; ++n) {
                    const float4 v = xp[n * KF4 + d4];
                    acc[n] += wv.x * v.x + wv.y * v.y + wv.z * v.z + wv.w * v.w;
                }
            }
            if (g == 0) {
                #pragma unroll
                for (int n = 0; n < 8; ++n)
                    agg[(size_t)(n0 + n) * 64 + lane] = acc[n] + bj;
            } else {
                const size_t co = (size_t)(g - 1) * 64 + lane;
                #pragma unroll
                for (int n = 0; n < 8; ++n)
                    hb[(size_t)(n0 + n) * 128 + co] = acc[n];
            }
        } else {
            for (int n = n0; n < nNodes; ++n) {
                float a = 0.f;
                for (int d4 = 0; d4 < KF4; ++d4) {
                    const float4 wv = wrow[d4 ^ jx];
                    const float4 v =
                        reinterpret_cast<const float4*>(x + (size_t)n * K)[d4];
                    a += wv.x * v.x + wv.y * v.y + wv.z * v.z + wv.w * v.w;
                }
                if (g == 0) agg[(size_t)n * 64 + lane] = a + bj;
                else        hb[(size_t)n * 128 + (size_t)(g - 1) * 64 + lane] = a;
            }
        }
    }
}

__global__ __launch_bounds__(256) void rgcn_edge(
    const float* __restrict__ hb,   // [N][2][64]
    const float* __restrict__ comp, // [R][2]
    const int* __restrict__ src,
    const int* __restrict__ dst,
    const int* __restrict__ et,
    float* __restrict__ agg,        // [N][64]
    int nEdges)
{
    const int lane = threadIdx.x & 63;
    const int wid = (blockIdx.x * 256 + threadIdx.x) >> 6;
    const int stride = gridDim.x * 4;
    for (int e = wid; e < nEdges; e += stride) {
        const int s = src[e];
        const int d = dst[e];
        const int t = et[e];
        const float c0 = comp[2 * t];
        const float c1 = comp[2 * t + 1];
        const float* __restrict__ row = hb + (size_t)s * 128;
        const float v = c0 * row[lane] + c1 * row[64 + lane];
        atomicAdd(agg + (size_t)d * 64 + lane, v);
    }
}

__global__ __launch_bounds__(256) void act_tanh4(float* __restrict__ a, int n4)
{
    int i = blockIdx.x * 256 + threadIdx.x;
    const int stride = gridDim.x * 256;
    float4* __restrict__ p = reinterpret_cast<float4*>(a);
    for (; i < n4; i += stride) {
        float4 v = p[i];
        v.x = tanhf(v.x); v.y = tanhf(v.y);
        v.z = tanhf(v.z); v.w = tanhf(v.w);
        p[i] = v;
    }
}

__global__ __launch_bounds__(256) void act_relu4(float* __restrict__ a, int n4)
{
    int i = blockIdx.x * 256 + threadIdx.x;
    const int stride = gridDim.x * 256;
    float4* __restrict__ p = reinterpret_cast<float4*>(a);
    for (; i < n4; i += stride) {
        float4 v = p[i];
        v.x = fmaxf(v.x, 0.f); v.y = fmaxf(v.y, 0.f);
        v.z = fmaxf(v.z, 0.f); v.w = fmaxf(v.w, 0.f);
        p[i] = v;
    }
}

extern "C" void kernel_launch(void* const* d_in, const int* in_sizes, int n_in,
                              void* d_out, int out_size, void* d_ws, size_t ws_size,
                              hipStream_t stream)
{
    const float* node_emb = (const float*)d_in[0];   // [N][128]
    const float* basis1   = (const float*)d_in[1];   // [2][128][64]
    const float* comp1    = (const float*)d_in[2];   // [R][2]
    const float* loop_w1  = (const float*)d_in[3];   // [128][64]
    const float* bias1    = (const float*)d_in[4];   // [64]
    const float* basis2   = (const float*)d_in[5];   // [2][64][64]
    const float* comp2    = (const float*)d_in[6];   // [R][2]
    const float* loop_w2  = (const float*)d_in[7];   // [64][64]
    const float* bias2    = (const float*)d_in[8];   // [64]
    const int*   src      = (const int*)d_in[9];     // [E]
    const int*   dst      = (const int*)d_in[10];    // [E]
    const int*   et       = (const int*)d_in[11];    // [E]

    const int N = in_sizes[0] / 128;
    const int E = in_sizes[9];

    float* out  = (float*)d_out;                 // [N][64] (also layer-2 agg)
    float* hb   = (float*)d_ws;                  // [N][2][64], reused per layer
    float* agg1 = hb + (size_t)N * 128;          // [N][64] -> h after tanh

    const dim3 dgrid(512, 3, 1);

    // ---- layer 1 ----
    rgcn_dense<128><<<dgrid, 256, 0, stream>>>(node_emb, loop_w1, basis1, bias1,
                                               agg1, hb, N);
    rgcn_edge<<<2048, 256, 0, stream>>>(hb, comp1, src, dst, et, agg1, E);
    act_tanh4<<<1024, 256, 0, stream>>>(agg1, (N * 64) / 4);

    // ---- layer 2 ----
    rgcn_dense<64><<<dgrid, 256, 0, stream>>>(agg1, loop_w2, basis2, bias2,
                                              out, hb, N);
    rgcn_edge<<<2048, 256, 0, stream>>>(hb, comp2, src, dst, et, out, E);
    act_relu4<<<1024, 256, 0, stream>>>(out, (N * 64) / 4);
}

// Round 3
// 572.043 us; speedup vs baseline: 1.5282x; 1.5282x over previous
//
#include <hip/hip_runtime.h>
#include <math.h>

// ---------------------------------------------------------------------------
// R-GCN (basis decomposition, B=2), 2 layers.
//   C[n, 0:192] = x[n,:] @ [loop_w | basis0 | basis1]   (dense)
//   agg = C[:,0:64]+bias ;  hb = C[:,64:192]
//   agg[dst] += sum_b comp[et,b]*hb[src,b,:]            (edge, atomics)
//   h' = act(agg)
//
// Dense: lane = node. 64 node-rows staged once in LDS (float4, XOR-swizzled
// -> optimal 8-phase ds_read_b128). Weights read via wave-uniform scalar
// loads (wid forced to SGPR with readfirstlane) -> v_fmac_f32 with SGPR
// operand, no per-lane W traffic. Each wave: 3 chunks of 16 cols, acc[16].
// tanh is fused into layer-2's staging load.
// ---------------------------------------------------------------------------

template<int K, bool ACT_TANH>
__global__ __launch_bounds__(256) void rgcn_dense(
    const float* __restrict__ x,      // [nNodes][K]
    const float* __restrict__ loopw,  // [K][64]
    const float* __restrict__ basis,  // [2][K][64]
    const float* __restrict__ bias,   // [64]
    float* __restrict__ agg,          // [nNodes][64]
    float* __restrict__ hb,           // [nNodes][128]
    int nNodes)
{
    constexpr int KF4 = K / 4;
    __shared__ float4 xl[64 * KF4];   // 64 rows, XOR-swizzled within row
    const int n0 = blockIdx.x * 64;

    // ---- stage x rows (coalesced); optionally apply tanh (layer 2) ----
    const float4* __restrict__ xg = reinterpret_cast<const float4*>(x);
    for (int idx = threadIdx.x; idx < 64 * KF4; idx += 256) {
        const int row = idx / KF4;
        const int k4  = idx % KF4;
        float4 v = make_float4(0.f, 0.f, 0.f, 0.f);
        if (n0 + row < nNodes) v = xg[(size_t)(n0 + row) * KF4 + k4];
        if (ACT_TANH) {
            v.x = tanhf(v.x); v.y = tanhf(v.y);
            v.z = tanhf(v.z); v.w = tanhf(v.w);
        }
        xl[row * KF4 + (k4 ^ (row & 7))] = v;
    }
    __syncthreads();

    const int lane = threadIdx.x & 63;
    const int wid  = __builtin_amdgcn_readfirstlane(threadIdx.x >> 6); // SGPR
    const int n    = n0 + lane;
    const bool valid = n < nNodes;
    const int jx = lane & 7;
    const float4* __restrict__ xrow = &xl[lane * KF4];

    #pragma unroll
    for (int c3 = 0; c3 < 3; ++c3) {
        // chunk = wid + 4*c3 in 0..11; cols jbase..jbase+15
        const int jbase = (wid + 4 * c3) * 16;        // uniform (SGPR)
        const float* __restrict__ Wc =
            (c3 == 0 ? loopw : basis + (size_t)(c3 - 1) * K * 64) + (jbase & 63);

        float acc[16];
        #pragma unroll
        for (int j = 0; j < 16; ++j) acc[j] = 0.f;

        #pragma unroll 4
        for (int k4 = 0; k4 < KF4; ++k4) {
            const float4 xv = xrow[k4 ^ jx];          // ds_read_b128
            #pragma unroll
            for (int kk = 0; kk < 4; ++kk) {
                const float xs = (kk == 0) ? xv.x : (kk == 1) ? xv.y
                               : (kk == 2) ? xv.z : xv.w;
                const float* __restrict__ wr = Wc + (size_t)(4 * k4 + kk) * 64;
                #pragma unroll
                for (int j = 0; j < 16; ++j)          // uniform -> s_load
                    acc[j] = fmaf(xs, wr[j], acc[j]);
            }
        }

        if (valid) {
            if (c3 == 0) {
                float* __restrict__ dst = agg + (size_t)n * 64 + jbase;
                #pragma unroll
                for (int j4 = 0; j4 < 4; ++j4) {
                    float4 o;
                    o.x = acc[4 * j4 + 0] + bias[jbase + 4 * j4 + 0];
                    o.y = acc[4 * j4 + 1] + bias[jbase + 4 * j4 + 1];
                    o.z = acc[4 * j4 + 2] + bias[jbase + 4 * j4 + 2];
                    o.w = acc[4 * j4 + 3] + bias[jbase + 4 * j4 + 3];
                    reinterpret_cast<float4*>(dst)[j4] = o;
                }
            } else {
                float* __restrict__ dst = hb + (size_t)n * 128 + (jbase - 64);
                #pragma unroll
                for (int j4 = 0; j4 < 4; ++j4) {
                    float4 o;
                    o.x = acc[4 * j4 + 0];
                    o.y = acc[4 * j4 + 1];
                    o.z = acc[4 * j4 + 2];
                    o.w = acc[4 * j4 + 3];
                    reinterpret_cast<float4*>(dst)[j4] = o;
                }
            }
        }
    }
}

__global__ __launch_bounds__(256) void rgcn_edge(
    const float* __restrict__ hb,   // [N][128]
    const float* __restrict__ comp, // [R][2]
    const int* __restrict__ src,
    const int* __restrict__ dst,
    const int* __restrict__ et,
    float* __restrict__ agg,        // [N][64]
    int nEdges)
{
    const int lane = threadIdx.x & 63;
    const int wid = (blockIdx.x * 256 + threadIdx.x) >> 6;
    const int stride = gridDim.x * 4;
    for (int e = wid; e < nEdges; e += stride) {
        const int s = src[e];
        const int d = dst[e];
        const int t = et[e];
        const float c0 = comp[2 * t];
        const float c1 = comp[2 * t + 1];
        const float* __restrict__ row = hb + (size_t)s * 128;
        const float v = c0 * row[lane] + c1 * row[64 + lane];
        atomicAdd(agg + (size_t)d * 64 + lane, v);
    }
}

__global__ __launch_bounds__(256) void act_relu4(float* __restrict__ a, int n4)
{
    int i = blockIdx.x * 256 + threadIdx.x;
    const int stride = gridDim.x * 256;
    float4* __restrict__ p = reinterpret_cast<float4*>(a);
    for (; i < n4; i += stride) {
        float4 v = p[i];
        v.x = fmaxf(v.x, 0.f); v.y = fmaxf(v.y, 0.f);
        v.z = fmaxf(v.z, 0.f); v.w = fmaxf(v.w, 0.f);
        p[i] = v;
    }
}

extern "C" void kernel_launch(void* const* d_in, const int* in_sizes, int n_in,
                              void* d_out, int out_size, void* d_ws, size_t ws_size,
                              hipStream_t stream)
{
    const float* node_emb = (const float*)d_in[0];   // [N][128]
    const float* basis1   = (const float*)d_in[1];   // [2][128][64]
    const float* comp1    = (const float*)d_in[2];   // [R][2]
    const float* loop_w1  = (const float*)d_in[3];   // [128][64]
    const float* bias1    = (const float*)d_in[4];   // [64]
    const float* basis2   = (const float*)d_in[5];   // [2][64][64]
    const float* comp2    = (const float*)d_in[6];   // [R][2]
    const float* loop_w2  = (const float*)d_in[7];   // [64][64]
    const float* bias2    = (const float*)d_in[8];   // [64]
    const int*   src      = (const int*)d_in[9];     // [E]
    const int*   dst      = (const int*)d_in[10];    // [E]
    const int*   et       = (const int*)d_in[11];    // [E]

    const int N = in_sizes[0] / 128;
    const int E = in_sizes[9];

    float* out  = (float*)d_out;                 // [N][64] (also layer-2 agg)
    float* hb   = (float*)d_ws;                  // [N][128], reused per layer
    float* agg1 = hb + (size_t)N * 128;          // [N][64] raw; tanh applied
                                                 // on load inside dense<64>

    const int nBlk = (N + 63) / 64;

    // ---- layer 1 ----
    rgcn_dense<128, false><<<nBlk, 256, 0, stream>>>(
        node_emb, loop_w1, basis1, bias1, agg1, hb, N);
    rgcn_edge<<<2048, 256, 0, stream>>>(hb, comp1, src, dst, et, agg1, E);

    // ---- layer 2 (tanh fused into staging load of agg1) ----
    rgcn_dense<64, true><<<nBlk, 256, 0, stream>>>(
        agg1, loop_w2, basis2, bias2, out, hb, N);
    rgcn_edge<<<2048, 256, 0, stream>>>(hb, comp2, src, dst, et, out, E);
    act_relu4<<<1024, 256, 0, stream>>>(out, (N * 64) / 4);
}

// Round 4
// 407.851 us; speedup vs baseline: 2.1434x; 1.4026x over previous
//
#include <hip/hip_runtime.h>
#include <math.h>

// ---------------------------------------------------------------------------
// R-GCN (basis decomposition, B=2), 2 layers.
//   C[n, 0:192] = x[n,:] @ [loop_w | basis0 | basis1]   (dense)
//   self = C[:,0:64]+bias ;  hb = C[:,64:192]
//   out[n] = act(self[n] + sum_{e: dst=n} (c0[e]*hb[src,0,:]+c1[e]*hb[src,1,:]))
//
// Edge aggregation via device-built CSR (dst-indexed), built ONCE per call,
// shared by both layers. No float atomics: one wave per dst node, register
// accumulation, activation fused into the final write.
// ---------------------------------------------------------------------------

// ---------------- dense: C = x @ [loopw|basis0|basis1] ----------------------
template<int K>
__global__ __launch_bounds__(256) void rgcn_dense(
    const float* __restrict__ x,      // [nNodes][K]
    const float* __restrict__ loopw,  // [K][64]
    const float* __restrict__ basis,  // [2][K][64]
    const float* __restrict__ bias,   // [64]
    float* __restrict__ agg,          // [nNodes][64]  (self + bias)
    float* __restrict__ hb,           // [nNodes][128]
    int nNodes)
{
    constexpr int KF4 = K / 4;
    __shared__ float4 xl[64 * KF4];   // 64 rows, XOR-swizzled within row
    const int n0 = blockIdx.x * 64;

    const float4* __restrict__ xg = reinterpret_cast<const float4*>(x);
    for (int idx = threadIdx.x; idx < 64 * KF4; idx += 256) {
        const int row = idx / KF4;
        const int k4  = idx % KF4;
        float4 v = make_float4(0.f, 0.f, 0.f, 0.f);
        if (n0 + row < nNodes) v = xg[(size_t)(n0 + row) * KF4 + k4];
        xl[row * KF4 + (k4 ^ (row & 7))] = v;
    }
    __syncthreads();

    const int lane = threadIdx.x & 63;
    const int wid  = __builtin_amdgcn_readfirstlane(threadIdx.x >> 6); // SGPR
    const int n    = n0 + lane;
    const bool valid = n < nNodes;
    const int jx = lane & 7;
    const float4* __restrict__ xrow = &xl[lane * KF4];

    #pragma unroll
    for (int c3 = 0; c3 < 3; ++c3) {
        const int jbase = (wid + 4 * c3) * 16;        // uniform (SGPR)
        const float* __restrict__ Wc =
            (c3 == 0 ? loopw : basis + (size_t)(c3 - 1) * K * 64) + (jbase & 63);

        float acc[16];
        #pragma unroll
        for (int j = 0; j < 16; ++j) acc[j] = 0.f;

        #pragma unroll 4
        for (int k4 = 0; k4 < KF4; ++k4) {
            const float4 xv = xrow[k4 ^ jx];          // ds_read_b128
            #pragma unroll
            for (int kk = 0; kk < 4; ++kk) {
                const float xs = (kk == 0) ? xv.x : (kk == 1) ? xv.y
                               : (kk == 2) ? xv.z : xv.w;
                const float* __restrict__ wr = Wc + (size_t)(4 * k4 + kk) * 64;
                #pragma unroll
                for (int j = 0; j < 16; ++j)          // uniform -> s_load
                    acc[j] = fmaf(xs, wr[j], acc[j]);
            }
        }

        if (valid) {
            if (c3 == 0) {
                float* __restrict__ dst = agg + (size_t)n * 64 + jbase;
                #pragma unroll
                for (int j4 = 0; j4 < 4; ++j4) {
                    float4 o;
                    o.x = acc[4 * j4 + 0] + bias[jbase + 4 * j4 + 0];
                    o.y = acc[4 * j4 + 1] + bias[jbase + 4 * j4 + 1];
                    o.z = acc[4 * j4 + 2] + bias[jbase + 4 * j4 + 2];
                    o.w = acc[4 * j4 + 3] + bias[jbase + 4 * j4 + 3];
                    reinterpret_cast<float4*>(dst)[j4] = o;
                }
            } else {
                float* __restrict__ dst = hb + (size_t)n * 128 + (jbase - 64);
                #pragma unroll
                for (int j4 = 0; j4 < 4; ++j4) {
                    float4 o;
                    o.x = acc[4 * j4 + 0];
                    o.y = acc[4 * j4 + 1];
                    o.z = acc[4 * j4 + 2];
                    o.w = acc[4 * j4 + 3];
                    reinterpret_cast<float4*>(dst)[j4] = o;
                }
            }
        }
    }
}

// ---------------- CSR build ----------------------------------------------
__global__ __launch_bounds__(256) void csr_hist(
    const int* __restrict__ dst, int* __restrict__ deg, int nE)
{
    const int e = blockIdx.x * 256 + threadIdx.x;
    if (e < nE) atomicAdd(&deg[dst[e]], 1);
}

__global__ __launch_bounds__(256) void csr_reduce(
    const int* __restrict__ deg, int* __restrict__ partials, int n)
{
    __shared__ int sm[256];
    const int b = blockIdx.x, t = threadIdx.x;
    const int base = b * 1024 + t * 4;
    int s = 0;
    if (base + 3 < n) {
        const int4 v = *reinterpret_cast<const int4*>(deg + base);
        s = v.x + v.y + v.z + v.w;
    } else {
        for (int k = 0; k < 4; ++k) if (base + k < n) s += deg[base + k];
    }
    sm[t] = s; __syncthreads();
    for (int off = 128; off > 0; off >>= 1) {
        if (t < off) sm[t] += sm[t + off];
        __syncthreads();
    }
    if (t == 0) partials[b] = sm[0];
}

__global__ __launch_bounds__(256) void csr_scan_part(
    int* __restrict__ partials, int nC)
{
    __shared__ int sm[256];
    const int t = threadIdx.x;
    sm[t] = (t < nC) ? partials[t] : 0;
    __syncthreads();
    for (int off = 1; off < 256; off <<= 1) {
        const int u = (t >= off) ? sm[t - off] : 0;
        __syncthreads();
        sm[t] += u;
        __syncthreads();
    }
    if (t < nC) partials[t] = (t ? sm[t - 1] : 0);   // exclusive
}

__global__ __launch_bounds__(256) void csr_scan_final(
    const int* __restrict__ deg, const int* __restrict__ partials,
    int* __restrict__ rowptr, int n)
{
    __shared__ int sm[256];
    const int b = blockIdx.x, t = threadIdx.x;
    const int base = b * 1024 + t * 4;
    int e0 = 0, e1 = 0, e2 = 0, e3 = 0;
    if (base + 3 < n) {
        const int4 v = *reinterpret_cast<const int4*>(deg + base);
        e0 = v.x; e1 = v.y; e2 = v.z; e3 = v.w;
    } else {
        if (base + 0 < n) e0 = deg[base + 0];
        if (base + 1 < n) e1 = deg[base + 1];
        if (base + 2 < n) e2 = deg[base + 2];
        if (base + 3 < n) e3 = deg[base + 3];
    }
    sm[t] = e0 + e1 + e2 + e3;
    __syncthreads();
    for (int off = 1; off < 256; off <<= 1) {
        const int u = (t >= off) ? sm[t - off] : 0;
        __syncthreads();
        sm[t] += u;
        __syncthreads();
    }
    int pre = partials[b] + (t ? sm[t - 1] : 0);
    if (base + 0 < n) rowptr[base + 0] = pre;
    if (base + 1 < n) rowptr[base + 1] = pre + e0;
    if (base + 2 < n) rowptr[base + 2] = pre + e0 + e1;
    if (base + 3 < n) rowptr[base + 3] = pre + e0 + e1 + e2;
}

// After this kernel rowptr[n] = end-of-segment(n) (orig rowptr[n+1]).
__global__ __launch_bounds__(256) void csr_scatter(
    const int* __restrict__ src, const int* __restrict__ dst,
    const int* __restrict__ et, int* __restrict__ cursor /* = rowptr */,
    unsigned* __restrict__ packed, int nE)
{
    const int e = blockIdx.x * 256 + threadIdx.x;
    if (e < nE) {
        const int p = atomicAdd(&cursor[dst[e]], 1);
        packed[p] = ((unsigned)src[e] << 6) | (unsigned)et[e];   // R=50 < 64
    }
}

// ---------------- edge aggregation: one wave per dst node ------------------
template<int ACT>   // 0 = tanh, 1 = relu
__global__ __launch_bounds__(256) void rgcn_agg(
    const float* __restrict__ hb,       // [N][128]
    const float* __restrict__ comp,     // [R][2]
    const int* __restrict__ rowptr,     // post-scatter: rowptr[n] = end(n)
    const unsigned* __restrict__ packed,// [E] (src<<6 | et), grouped by dst
    float* __restrict__ io,             // in: self+bias, out: act(self+agg)
    int nNodes)
{
    const int lane = threadIdx.x & 63;
    const int w  = (blockIdx.x * 256 + threadIdx.x) >> 6;
    const int nW = (gridDim.x * 256) >> 6;
    for (int n = w; n < nNodes; n += nW) {
        const int end = rowptr[n];
        const int beg = (n == 0) ? 0 : rowptr[n - 1];
        float acc = 0.f;
        for (int base = beg; base < end; base += 64) {
            const int cnt = min(64, end - base);
            int sp = 0; float c0 = 0.f, c1 = 0.f;
            if (lane < cnt) {
                const unsigned p = packed[base + lane];
                sp = (int)(p >> 6);
                const int t = (int)(p & 63u);
                c0 = comp[2 * t]; c1 = comp[2 * t + 1];
            }
            int i = 0;
            for (; i + 2 <= cnt; i += 2) {
                const int   sA = __shfl(sp, i),     sB = __shfl(sp, i + 1);
                const float a0 = __shfl(c0, i),     a1 = __shfl(c1, i);
                const float b0 = __shfl(c0, i + 1), b1 = __shfl(c1, i + 1);
                const float* __restrict__ rA = hb + (size_t)sA * 128;
                const float* __restrict__ rB = hb + (size_t)sB * 128;
                const float vA0 = rA[lane], vA1 = rA[64 + lane];
                const float vB0 = rB[lane], vB1 = rB[64 + lane];
                acc += a0 * vA0 + a1 * vA1;
                acc += b0 * vB0 + b1 * vB1;
            }
            if (i < cnt) {
                const int   sA = __shfl(sp, i);
                const float a0 = __shfl(c0, i), a1 = __shfl(c1, i);
                const float* __restrict__ rA = hb + (size_t)sA * 128;
                acc += a0 * rA[lane] + a1 * rA[64 + lane];
            }
        }
        const float self = io[(size_t)n * 64 + lane];
        float o = self + acc;
        o = (ACT == 0) ? tanhf(o) : fmaxf(o, 0.f);
        io[(size_t)n * 64 + lane] = o;
    }
}

// ---------------------------------------------------------------------------
extern "C" void kernel_launch(void* const* d_in, const int* in_sizes, int n_in,
                              void* d_out, int out_size, void* d_ws, size_t ws_size,
                              hipStream_t stream)
{
    const float* node_emb = (const float*)d_in[0];   // [N][128]
    const float* basis1   = (const float*)d_in[1];   // [2][128][64]
    const float* comp1    = (const float*)d_in[2];   // [R][2]
    const float* loop_w1  = (const float*)d_in[3];   // [128][64]
    const float* bias1    = (const float*)d_in[4];   // [64]
    const float* basis2   = (const float*)d_in[5];   // [2][64][64]
    const float* comp2    = (const float*)d_in[6];   // [R][2]
    const float* loop_w2  = (const float*)d_in[7];   // [64][64]
    const float* bias2    = (const float*)d_in[8];   // [64]
    const int*   src      = (const int*)d_in[9];     // [E]
    const int*   dst      = (const int*)d_in[10];    // [E]
    const int*   et       = (const int*)d_in[11];    // [E]

    const int N = in_sizes[0] / 128;
    const int E = in_sizes[9];

    float* out = (float*)d_out;                      // [N][64]

    // workspace layout
    float*    hb       = (float*)d_ws;               // N*128 f
    float*    h        = hb + (size_t)N * 128;       // N*64 f
    unsigned* packed   = (unsigned*)(h + (size_t)N * 64); // E u32
    int*      deg      = (int*)(packed + E);         // N
    int*      rowptr   = deg + N;                    // N
    int*      partials = rowptr + N;                 // 256

    const int nBlkDense = (N + 63) / 64;
    const int nBlkE     = (E + 255) / 256;
    const int nC        = (N + 1023) / 1024;         // scan chunks (<=256)
    const int nBlkAgg   = (N + 3) / 4;               // 1 wave per node

    // ---- CSR build (shared by both layers) ----
    hipMemsetAsync(deg, 0, (size_t)N * sizeof(int), stream);
    csr_hist      <<<nBlkE, 256, 0, stream>>>(dst, deg, E);
    csr_reduce    <<<nC,    256, 0, stream>>>(deg, partials, N);
    csr_scan_part <<<1,     256, 0, stream>>>(partials, nC);
    csr_scan_final<<<nC,    256, 0, stream>>>(deg, partials, rowptr, N);
    csr_scatter   <<<nBlkE, 256, 0, stream>>>(src, dst, et, rowptr, packed, E);

    // ---- layer 1 ----
    rgcn_dense<128><<<nBlkDense, 256, 0, stream>>>(
        node_emb, loop_w1, basis1, bias1, h, hb, N);
    rgcn_agg<0><<<nBlkAgg, 256, 0, stream>>>(hb, comp1, rowptr, packed, h, N);

    // ---- layer 2 ----
    rgcn_dense<64><<<nBlkDense, 256, 0, stream>>>(
        h, loop_w2, basis2, bias2, out, hb, N);
    rgcn_agg<1><<<nBlkAgg, 256, 0, stream>>>(hb, comp2, rowptr, packed, out, N);
}

// Round 5
// 386.303 us; speedup vs baseline: 2.2630x; 1.0558x over previous
//
#include <hip/hip_runtime.h>
#include <math.h>

// ---------------------------------------------------------------------------
// R-GCN (basis decomposition, B=2), 2 layers.
//   C[n, 0:192] = x[n,:] @ [loop_w | basis0 | basis1]   (dense, MFMA bf16x3)
//   self = C[:,0:64]+bias ;  hb = C[:,64:192]
//   out[n] = act(self[n] + sum_{e: dst=n} c0*hb[src,0,:]+c1*hb[src,1,:])
//
// Dense via matrix cores with fp32 emulation: x = xh + xl, w = wh + wl
// (bf16 hi/lo, RNE); C = xh*wh + xh*wl + xl*wh  (xl*wl ~ 2^-18, dropped).
// Edge aggregation via device-built CSR (dst-indexed), no float atomics.
// ---------------------------------------------------------------------------

typedef short          short8 __attribute__((ext_vector_type(8)));
typedef float          f32x4  __attribute__((ext_vector_type(4)));
typedef unsigned short u16;

static __device__ __forceinline__ u16 bf16_rne(float x) {
    unsigned u = __float_as_uint(x);
    return (u16)((u + 0x7fffu + ((u >> 16) & 1u)) >> 16);
}
static __device__ __forceinline__ float bf16_f32(u16 h) {
    return __uint_as_float(((unsigned)h) << 16);
}

// ---------------- W pre-convert: Wt[192][K] bf16 hi/lo (transposed) --------
__global__ __launch_bounds__(256) void wconv(
    const float* __restrict__ loopw1, const float* __restrict__ basis1,
    const float* __restrict__ loopw2, const float* __restrict__ basis2,
    u16* __restrict__ wt1h, u16* __restrict__ wt1l,
    u16* __restrict__ wt2h, u16* __restrict__ wt2l)
{
    const int tid = blockIdx.x * 256 + threadIdx.x;
    if (tid < 192 * 128) {                       // layer 1, K=128
        const int j = tid >> 7, k = tid & 127;
        const float w = (j < 64)
            ? loopw1[k * 64 + j]
            : basis1[(size_t)((j - 64) >> 6) * (128 * 64) + k * 64 + ((j - 64) & 63)];
        const u16 h = bf16_rne(w);
        wt1h[tid] = h;
        wt1l[tid] = bf16_rne(w - bf16_f32(h));
    }
    if (tid < 192 * 64) {                        // layer 2, K=64
        const int j = tid >> 6, k = tid & 63;
        const float w = (j < 64)
            ? loopw2[k * 64 + j]
            : basis2[(size_t)((j - 64) >> 6) * (64 * 64) + k * 64 + ((j - 64) & 63)];
        const u16 h = bf16_rne(w);
        wt2h[tid] = h;
        wt2l[tid] = bf16_rne(w - bf16_f32(h));
    }
}

// ---------------- dense: 128 nodes/block, MFMA 16x16x32 bf16 x3 ------------
template<int K>
__global__ __launch_bounds__(256, 2) void rgcn_dense_mfma(
    const float* __restrict__ x,     // [N][K] f32
    const u16* __restrict__ wth,     // [192][K] bf16 hi (transposed)
    const u16* __restrict__ wtl,     // [192][K] bf16 lo
    const float* __restrict__ bias,  // [64]
    float* __restrict__ self,        // [N][64]  = x@loopw + bias
    float* __restrict__ hb,          // [N][128] = x@basis
    int nNodes)
{
    constexpr int KC  = K / 32;      // mfma K-steps
    constexpr int GPR = K / 8;       // 16B granules per row
    constexpr int GM  = GPR - 1;     // row-XOR mask (15 or 7)
    __shared__ u16 lds[2 * 128 * K]; // Xh then Xl

    const int n0 = blockIdx.x * 128;

    // ---- stage x -> bf16 hi/lo in LDS, granule-XOR swizzled ----
    for (int gi = threadIdx.x; gi < 128 * GPR; gi += 256) {
        const int row = gi / GPR, g = gi % GPR;
        const int n = n0 + row;
        float v[8];
        if (n < nNodes) {
            const float4 a = *reinterpret_cast<const float4*>(x + (size_t)n * K + g * 8);
            const float4 b = *reinterpret_cast<const float4*>(x + (size_t)n * K + g * 8 + 4);
            v[0] = a.x; v[1] = a.y; v[2] = a.z; v[3] = a.w;
            v[4] = b.x; v[5] = b.y; v[6] = b.z; v[7] = b.w;
        } else {
            #pragma unroll
            for (int i = 0; i < 8; ++i) v[i] = 0.f;
        }
        short8 hv, lv;
        #pragma unroll
        for (int i = 0; i < 8; ++i) {
            const u16 h = bf16_rne(v[i]);
            hv[i] = (short)h;
            lv[i] = (short)bf16_rne(v[i] - bf16_f32(h));
        }
        const int gp = g ^ (row & GM);
        *reinterpret_cast<short8*>(&lds[(size_t)row * K + gp * 8]) = hv;
        *reinterpret_cast<short8*>(&lds[(size_t)(128 + row) * K + gp * 8]) = lv;
    }
    __syncthreads();

    const int lane = threadIdx.x & 63;
    const int w    = threadIdx.x >> 6;
    const int rl   = lane & 15;      // A row / B col / D col
    const int kb   = lane >> 4;      // k-block

    // ---- A fragments (all K, both row-groups, hi+lo) in registers ----
    short8 Ah[2][KC], Al[2][KC];
    #pragma unroll
    for (int rg = 0; rg < 2; ++rg) {
        const int row = w * 32 + rg * 16 + rl;
        const u16* bh = &lds[(size_t)row * K];
        const u16* bl = &lds[(size_t)(128 + row) * K];
        #pragma unroll
        for (int kc = 0; kc < KC; ++kc) {
            const int gp = (kc * 4 + kb) ^ (row & GM);
            Ah[rg][kc] = *reinterpret_cast<const short8*>(bh + gp * 8);
            Al[rg][kc] = *reinterpret_cast<const short8*>(bl + gp * 8);
        }
    }

    f32x4 acc[2][12];
    #pragma unroll
    for (int rg = 0; rg < 2; ++rg)
        #pragma unroll
        for (int j = 0; j < 12; ++j)
            acc[rg][j] = (f32x4){0.f, 0.f, 0.f, 0.f};

    #pragma unroll
    for (int j16 = 0; j16 < 12; ++j16) {
        const u16* wh = wth + (size_t)(j16 * 16 + rl) * K + kb * 8;
        const u16* wl = wtl + (size_t)(j16 * 16 + rl) * K + kb * 8;
        #pragma unroll
        for (int kc = 0; kc < KC; ++kc) {
            const short8 Bh = *reinterpret_cast<const short8*>(wh + kc * 32);
            const short8 Bl = *reinterpret_cast<const short8*>(wl + kc * 32);
            #pragma unroll
            for (int rg = 0; rg < 2; ++rg) {
                acc[rg][j16] = __builtin_amdgcn_mfma_f32_16x16x32_bf16(
                    Ah[rg][kc], Bh, acc[rg][j16], 0, 0, 0);
                acc[rg][j16] = __builtin_amdgcn_mfma_f32_16x16x32_bf16(
                    Ah[rg][kc], Bl, acc[rg][j16], 0, 0, 0);
                acc[rg][j16] = __builtin_amdgcn_mfma_f32_16x16x32_bf16(
                    Al[rg][kc], Bh, acc[rg][j16], 0, 0, 0);
            }
        }
    }

    // ---- epilogue: D[(kb*4+r)][rl] per 16-row group ----
    #pragma unroll
    for (int rg = 0; rg < 2; ++rg) {
        const int rowbase = n0 + w * 32 + rg * 16 + kb * 4;
        #pragma unroll
        for (int j16 = 0; j16 < 4; ++j16) {       // cols 0..63 -> self + bias
            const float bj = bias[j16 * 16 + rl];
            #pragma unroll
            for (int r = 0; r < 4; ++r) {
                const int row = rowbase + r;
                if (row < nNodes)
                    self[(size_t)row * 64 + j16 * 16 + rl] = acc[rg][j16][r] + bj;
            }
        }
        #pragma unroll
        for (int j16 = 4; j16 < 12; ++j16) {      // cols 64..191 -> hb
            #pragma unroll
            for (int r = 0; r < 4; ++r) {
                const int row = rowbase + r;
                if (row < nNodes)
                    hb[(size_t)row * 128 + (j16 - 4) * 16 + rl] = acc[rg][j16][r];
            }
        }
    }
}

// ---------------- CSR build ------------------------------------------------
__global__ __launch_bounds__(256) void csr_hist(
    const int* __restrict__ dst, int* __restrict__ deg, int nE)
{
    const int e = blockIdx.x * 256 + threadIdx.x;
    if (e < nE) atomicAdd(&deg[dst[e]], 1);
}

__global__ __launch_bounds__(256) void csr_reduce(
    const int* __restrict__ deg, int* __restrict__ partials, int n)
{
    __shared__ int sm[256];
    const int b = blockIdx.x, t = threadIdx.x;
    const int base = b * 1024 + t * 4;
    int s = 0;
    if (base + 3 < n) {
        const int4 v = *reinterpret_cast<const int4*>(deg + base);
        s = v.x + v.y + v.z + v.w;
    } else {
        for (int k = 0; k < 4; ++k) if (base + k < n) s += deg[base + k];
    }
    sm[t] = s; __syncthreads();
    for (int off = 128; off > 0; off >>= 1) {
        if (t < off) sm[t] += sm[t + off];
        __syncthreads();
    }
    if (t == 0) partials[b] = sm[0];
}

__global__ __launch_bounds__(256) void csr_scan_part(
    int* __restrict__ partials, int nC)
{
    __shared__ int sm[256];
    const int t = threadIdx.x;
    sm[t] = (t < nC) ? partials[t] : 0;
    __syncthreads();
    for (int off = 1; off < 256; off <<= 1) {
        const int u = (t >= off) ? sm[t - off] : 0;
        __syncthreads();
        sm[t] += u;
        __syncthreads();
    }
    if (t < nC) partials[t] = (t ? sm[t - 1] : 0);   // exclusive
}

__global__ __launch_bounds__(256) void csr_scan_final(
    const int* __restrict__ deg, const int* __restrict__ partials,
    int* __restrict__ rowptr, int n)
{
    __shared__ int sm[256];
    const int b = blockIdx.x, t = threadIdx.x;
    const int base = b * 1024 + t * 4;
    int e0 = 0, e1 = 0, e2 = 0, e3 = 0;
    if (base + 3 < n) {
        const int4 v = *reinterpret_cast<const int4*>(deg + base);
        e0 = v.x; e1 = v.y; e2 = v.z; e3 = v.w;
    } else {
        if (base + 0 < n) e0 = deg[base + 0];
        if (base + 1 < n) e1 = deg[base + 1];
        if (base + 2 < n) e2 = deg[base + 2];
        if (base + 3 < n) e3 = deg[base + 3];
    }
    sm[t] = e0 + e1 + e2 + e3;
    __syncthreads();
    for (int off = 1; off < 256; off <<= 1) {
        const int u = (t >= off) ? sm[t - off] : 0;
        __syncthreads();
        sm[t] += u;
        __syncthreads();
    }
    int pre = partials[b] + (t ? sm[t - 1] : 0);
    if (base + 0 < n) rowptr[base + 0] = pre;
    if (base + 1 < n) rowptr[base + 1] = pre + e0;
    if (base + 2 < n) rowptr[base + 2] = pre + e0 + e1;
    if (base + 3 < n) rowptr[base + 3] = pre + e0 + e1 + e2;
}

// After this kernel rowptr[n] = end-of-segment(n).
__global__ __launch_bounds__(256) void csr_scatter(
    const int* __restrict__ src, const int* __restrict__ dst,
    const int* __restrict__ et, int* __restrict__ cursor /* = rowptr */,
    unsigned* __restrict__ packed, int nE)
{
    const int e = blockIdx.x * 256 + threadIdx.x;
    if (e < nE) {
        const int p = atomicAdd(&cursor[dst[e]], 1);
        packed[p] = ((unsigned)src[e] << 6) | (unsigned)et[e];   // R=50 < 64
    }
}

// ---------------- edge aggregation: one wave per dst node ------------------
template<int ACT>   // 0 = tanh, 1 = relu
__global__ __launch_bounds__(256) void rgcn_agg(
    const float* __restrict__ hb,       // [N][128]
    const float* __restrict__ comp,     // [R][2]
    const int* __restrict__ rowptr,     // rowptr[n] = end(n)
    const unsigned* __restrict__ packed,// [E] (src<<6 | et), grouped by dst
    float* __restrict__ io,             // in: self+bias, out: act(self+agg)
    int nNodes)
{
    const int lane = threadIdx.x & 63;
    const int w  = (blockIdx.x * 256 + threadIdx.x) >> 6;
    const int nW = (gridDim.x * 256) >> 6;
    for (int n = w; n < nNodes; n += nW) {
        const int end = rowptr[n];
        const int beg = (n == 0) ? 0 : rowptr[n - 1];
        float acc = 0.f;
        for (int base = beg; base < end; base += 64) {
            const int cnt = min(64, end - base);
            int sp = 0; float c0 = 0.f, c1 = 0.f;
            if (lane < cnt) {
                const unsigned p = packed[base + lane];
                sp = (int)(p >> 6);
                const int t = (int)(p & 63u);
                c0 = comp[2 * t]; c1 = comp[2 * t + 1];
            }
            int i = 0;
            for (; i + 2 <= cnt; i += 2) {
                const int   sA = __shfl(sp, i),     sB = __shfl(sp, i + 1);
                const float a0 = __shfl(c0, i),     a1 = __shfl(c1, i);
                const float b0 = __shfl(c0, i + 1), b1 = __shfl(c1, i + 1);
                const float* __restrict__ rA = hb + (size_t)sA * 128;
                const float* __restrict__ rB = hb + (size_t)sB * 128;
                const float vA0 = rA[lane], vA1 = rA[64 + lane];
                const float vB0 = rB[lane], vB1 = rB[64 + lane];
                acc += a0 * vA0 + a1 * vA1;
                acc += b0 * vB0 + b1 * vB1;
            }
            if (i < cnt) {
                const int   sA = __shfl(sp, i);
                const float a0 = __shfl(c0, i), a1 = __shfl(c1, i);
                const float* __restrict__ rA = hb + (size_t)sA * 128;
                acc += a0 * rA[lane] + a1 * rA[64 + lane];
            }
        }
        const float self = io[(size_t)n * 64 + lane];
        float o = self + acc;
        o = (ACT == 0) ? tanhf(o) : fmaxf(o, 0.f);
        io[(size_t)n * 64 + lane] = o;
    }
}

// ---------------------------------------------------------------------------
extern "C" void kernel_launch(void* const* d_in, const int* in_sizes, int n_in,
                              void* d_out, int out_size, void* d_ws, size_t ws_size,
                              hipStream_t stream)
{
    const float* node_emb = (const float*)d_in[0];   // [N][128]
    const float* basis1   = (const float*)d_in[1];   // [2][128][64]
    const float* comp1    = (const float*)d_in[2];   // [R][2]
    const float* loop_w1  = (const float*)d_in[3];   // [128][64]
    const float* bias1    = (const float*)d_in[4];   // [64]
    const float* basis2   = (const float*)d_in[5];   // [2][64][64]
    const float* comp2    = (const float*)d_in[6];   // [R][2]
    const float* loop_w2  = (const float*)d_in[7];   // [64][64]
    const float* bias2    = (const float*)d_in[8];   // [64]
    const int*   src      = (const int*)d_in[9];     // [E]
    const int*   dst      = (const int*)d_in[10];    // [E]
    const int*   et       = (const int*)d_in[11];    // [E]

    const int N = in_sizes[0] / 128;
    const int E = in_sizes[9];

    float* out = (float*)d_out;                      // [N][64]

    // workspace layout (all 16B-aligned)
    float*    hb       = (float*)d_ws;               // N*128 f
    float*    h        = hb + (size_t)N * 128;       // N*64 f
    unsigned* packed   = (unsigned*)(h + (size_t)N * 64); // E u32
    int*      deg      = (int*)(packed + E);         // N
    int*      rowptr   = deg + N;                    // N
    int*      partials = rowptr + N;                 // 256
    u16*      wt1h     = (u16*)(partials + 256);     // 192*128
    u16*      wt1l     = wt1h + 192 * 128;
    u16*      wt2h     = wt1l + 192 * 128;           // 192*64
    u16*      wt2l     = wt2h + 192 * 64;

    const int nBlkDense = (N + 127) / 128;
    const int nBlkE     = (E + 255) / 256;
    const int nC        = (N + 1023) / 1024;         // scan chunks (<=256)
    const int nBlkAgg   = (N + 3) / 4;               // 1 wave per node

    // ---- W pre-convert (bf16 hi/lo, transposed) ----
    wconv<<<96, 256, 0, stream>>>(loop_w1, basis1, loop_w2, basis2,
                                  wt1h, wt1l, wt2h, wt2l);

    // ---- CSR build (shared by both layers) ----
    hipMemsetAsync(deg, 0, (size_t)N * sizeof(int), stream);
    csr_hist      <<<nBlkE, 256, 0, stream>>>(dst, deg, E);
    csr_reduce    <<<nC,    256, 0, stream>>>(deg, partials, N);
    csr_scan_part <<<1,     256, 0, stream>>>(partials, nC);
    csr_scan_final<<<nC,    256, 0, stream>>>(deg, partials, rowptr, N);
    csr_scatter   <<<nBlkE, 256, 0, stream>>>(src, dst, et, rowptr, packed, E);

    // ---- layer 1 ----
    rgcn_dense_mfma<128><<<nBlkDense, 256, 0, stream>>>(
        node_emb, wt1h, wt1l, bias1, h, hb, N);
    rgcn_agg<0><<<nBlkAgg, 256, 0, stream>>>(hb, comp1, rowptr, packed, h, N);

    // ---- layer 2 ----
    rgcn_dense_mfma<64><<<nBlkDense, 256, 0, stream>>>(
        h, wt2h, wt2l, bias2, out, hb, N);
    rgcn_agg<1><<<nBlkAgg, 256, 0, stream>>>(hb, comp2, rowptr, packed, out, N);
}

// Round 6
// 347.028 us; speedup vs baseline: 2.5191x; 1.1132x over previous
//
#include <hip/hip_runtime.h>
#include <math.h>

// ---------------------------------------------------------------------------
// R-GCN (basis decomposition, B=2), 2 layers.
//   C[n, 0:192] = x[n,:] @ [loop_w | basis0 | basis1]   (dense, MFMA bf16x3)
//   self = C[:,0:64]+bias ;  hb = C[:,64:192]
//   out[n] = act(self[n] + sum_{e: dst=n} c0*hb[src,0,:]+c1*hb[src,1,:])
//
// Dense via matrix cores with fp32 emulation: x = xh + xl, w = wh + wl
// (bf16 hi/lo, RNE); C = xh*wh + xh*wl + xl*wh  (xl*wl ~ 2^-18, dropped).
//   - A fragments loaded global->reg directly (x read once per block)
//   - W staged in LDS in two 96-col halves, granule-XOR swizzle (0-conflict
//     pattern verified in round 5), shared by all 8 waves of the block.
// Edge aggregation via device-built CSR (dst-indexed), no float atomics.
// ---------------------------------------------------------------------------

typedef short          short8 __attribute__((ext_vector_type(8)));
typedef float          f32x4  __attribute__((ext_vector_type(4)));
typedef unsigned short u16;

static __device__ __forceinline__ u16 bf16_rne(float x) {
    unsigned u = __float_as_uint(x);
    return (u16)((u + 0x7fffu + ((u >> 16) & 1u)) >> 16);
}
static __device__ __forceinline__ float bf16_f32(u16 h) {
    return __uint_as_float(((unsigned)h) << 16);
}

// ---------------- W pre-convert: Wt[192][K] bf16 hi/lo (transposed) --------
__global__ __launch_bounds__(256) void wconv(
    const float* __restrict__ loopw1, const float* __restrict__ basis1,
    const float* __restrict__ loopw2, const float* __restrict__ basis2,
    u16* __restrict__ wt1h, u16* __restrict__ wt1l,
    u16* __restrict__ wt2h, u16* __restrict__ wt2l)
{
    const int tid = blockIdx.x * 256 + threadIdx.x;
    if (tid < 192 * 128) {                       // layer 1, K=128
        const int j = tid >> 7, k = tid & 127;
        const float w = (j < 64)
            ? loopw1[k * 64 + j]
            : basis1[(size_t)((j - 64) >> 6) * (128 * 64) + k * 64 + ((j - 64) & 63)];
        const u16 h = bf16_rne(w);
        wt1h[tid] = h;
        wt1l[tid] = bf16_rne(w - bf16_f32(h));
    }
    if (tid < 192 * 64) {                        // layer 2, K=64
        const int j = tid >> 6, k = tid & 63;
        const float w = (j < 64)
            ? loopw2[k * 64 + j]
            : basis2[(size_t)((j - 64) >> 6) * (64 * 64) + k * 64 + ((j - 64) & 63)];
        const u16 h = bf16_rne(w);
        wt2h[tid] = h;
        wt2l[tid] = bf16_rne(w - bf16_f32(h));
    }
}

// ---------------- dense: 128 nodes/block, 8 waves, W in LDS ----------------
template<int K>
__global__ __launch_bounds__(512, 2) void rgcn_dense_mfma(
    const float* __restrict__ x,     // [N][K] f32
    const u16* __restrict__ wth,     // [192][K] bf16 hi (transposed)
    const u16* __restrict__ wtl,     // [192][K] bf16 lo
    const float* __restrict__ bias,  // [64]
    float* __restrict__ self,        // [N][64]  = x@loopw + bias
    float* __restrict__ hb,          // [N][128] = x@basis
    int nNodes)
{
    constexpr int KC  = K / 32;          // mfma K-steps
    constexpr int GW  = K / 8;           // 16B granules per (col,split)
    constexpr int GMW = GW - 1;          // granule XOR mask
    __shared__ u16 wlds[96 * 2 * K];     // one 96-col half of W (hi+lo)

    const int n0   = blockIdx.x * 128;
    const int lane = threadIdx.x & 63;
    const int w    = threadIdx.x >> 6;   // 0..7
    const int rl   = lane & 15;          // A row / B col / D col
    const int kb   = lane >> 4;          // k-block

    // ---- A fragments: global -> reg, convert to bf16 hi/lo ----
    const int row = n0 + w * 16 + rl;
    short8 Ah[KC], Al[KC];
    #pragma unroll
    for (int kc = 0; kc < KC; ++kc) {
        float v[8];
        if (row < nNodes) {
            const float* xp = x + (size_t)row * K + kc * 32 + kb * 8;
            const float4 a = *reinterpret_cast<const float4*>(xp);
            const float4 b = *reinterpret_cast<const float4*>(xp + 4);
            v[0] = a.x; v[1] = a.y; v[2] = a.z; v[3] = a.w;
            v[4] = b.x; v[5] = b.y; v[6] = b.z; v[7] = b.w;
        } else {
            #pragma unroll
            for (int i = 0; i < 8; ++i) v[i] = 0.f;
        }
        #pragma unroll
        for (int i = 0; i < 8; ++i) {
            const u16 h = bf16_rne(v[i]);
            Ah[kc][i] = (short)h;
            Al[kc][i] = (short)bf16_rne(v[i] - bf16_f32(h));
        }
    }

    f32x4 acc[12];
    #pragma unroll
    for (int j = 0; j < 12; ++j) acc[j] = (f32x4){0.f, 0.f, 0.f, 0.f};

    #pragma unroll
    for (int hf = 0; hf < 2; ++hf) {
        if (hf) __syncthreads();         // protect LDS before overwrite
        // ---- stage 96 cols of W (hi+lo) into LDS, XOR-swizzled ----
        for (int gi = threadIdx.x; gi < 96 * 2 * GW; gi += 512) {
            const int ch = gi / (2 * GW);
            const int r  = gi - ch * 2 * GW;
            const int s  = r / GW;
            const int g  = r - s * GW;
            const u16* sp = (s == 0 ? wth : wtl)
                          + (size_t)(hf * 96 + ch) * K + g * 8;
            const short8 vv = *reinterpret_cast<const short8*>(sp);
            *reinterpret_cast<short8*>(
                &wlds[((ch * 2 + s) * GW + (g ^ (ch & GMW))) * 8]) = vv;
        }
        __syncthreads();

        #pragma unroll
        for (int j16h = 0; j16h < 6; ++j16h) {
            const int ch = j16h * 16 + rl;
            const u16* bbase = &wlds[(ch * 2) * GW * 8];
            #pragma unroll
            for (int kc = 0; kc < KC; ++kc) {
                const int gp = (kc * 4 + kb) ^ (ch & GMW);
                const short8 Bh =
                    *reinterpret_cast<const short8*>(bbase + gp * 8);
                const short8 Bl =
                    *reinterpret_cast<const short8*>(bbase + (GW + gp) * 8);
                f32x4 a = acc[hf * 6 + j16h];
                a = __builtin_amdgcn_mfma_f32_16x16x32_bf16(Ah[kc], Bh, a, 0, 0, 0);
                a = __builtin_amdgcn_mfma_f32_16x16x32_bf16(Ah[kc], Bl, a, 0, 0, 0);
                a = __builtin_amdgcn_mfma_f32_16x16x32_bf16(Al[kc], Bh, a, 0, 0, 0);
                acc[hf * 6 + j16h] = a;
            }
        }
    }

    // ---- epilogue: D[(kb*4+r)][rl] ----
    const int rowbase = n0 + w * 16 + kb * 4;
    #pragma unroll
    for (int j16 = 0; j16 < 4; ++j16) {          // cols 0..63 -> self + bias
        const float bj = bias[j16 * 16 + rl];
        #pragma unroll
        for (int r = 0; r < 4; ++r) {
            const int rr = rowbase + r;
            if (rr < nNodes)
                self[(size_t)rr * 64 + j16 * 16 + rl] = acc[j16][r] + bj;
        }
    }
    #pragma unroll
    for (int j16 = 4; j16 < 12; ++j16) {         // cols 64..191 -> hb
        #pragma unroll
        for (int r = 0; r < 4; ++r) {
            const int rr = rowbase + r;
            if (rr < nNodes)
                hb[(size_t)rr * 128 + (j16 - 4) * 16 + rl] = acc[j16][r];
        }
    }
}

// ---------------- CSR build ------------------------------------------------
__global__ __launch_bounds__(256) void csr_hist(
    const int* __restrict__ dst, int* __restrict__ deg, int nE)
{
    const int e = blockIdx.x * 256 + threadIdx.x;
    if (e < nE) atomicAdd(&deg[dst[e]], 1);
}

__global__ __launch_bounds__(256) void csr_reduce(
    const int* __restrict__ deg, int* __restrict__ partials, int n)
{
    __shared__ int sm[256];
    const int b = blockIdx.x, t = threadIdx.x;
    const int base = b * 1024 + t * 4;
    int s = 0;
    if (base + 3 < n) {
        const int4 v = *reinterpret_cast<const int4*>(deg + base);
        s = v.x + v.y + v.z + v.w;
    } else {
        for (int k = 0; k < 4; ++k) if (base + k < n) s += deg[base + k];
    }
    sm[t] = s; __syncthreads();
    for (int off = 128; off > 0; off >>= 1) {
        if (t < off) sm[t] += sm[t + off];
        __syncthreads();
    }
    if (t == 0) partials[b] = sm[0];
}

__global__ __launch_bounds__(256) void csr_scan_part(
    int* __restrict__ partials, int nC)
{
    __shared__ int sm[256];
    const int t = threadIdx.x;
    sm[t] = (t < nC) ? partials[t] : 0;
    __syncthreads();
    for (int off = 1; off < 256; off <<= 1) {
        const int u = (t >= off) ? sm[t - off] : 0;
        __syncthreads();
        sm[t] += u;
        __syncthreads();
    }
    if (t < nC) partials[t] = (t ? sm[t - 1] : 0);   // exclusive
}

__global__ __launch_bounds__(256) void csr_scan_final(
    const int* __restrict__ deg, const int* __restrict__ partials,
    int* __restrict__ rowptr, int n)
{
    __shared__ int sm[256];
    const int b = blockIdx.x, t = threadIdx.x;
    const int base = b * 1024 + t * 4;
    int e0 = 0, e1 = 0, e2 = 0, e3 = 0;
    if (base + 3 < n) {
        const int4 v = *reinterpret_cast<const int4*>(deg + base);
        e0 = v.x; e1 = v.y; e2 = v.z; e3 = v.w;
    } else {
        if (base + 0 < n) e0 = deg[base + 0];
        if (base + 1 < n) e1 = deg[base + 1];
        if (base + 2 < n) e2 = deg[base + 2];
        if (base + 3 < n) e3 = deg[base + 3];
    }
    sm[t] = e0 + e1 + e2 + e3;
    __syncthreads();
    for (int off = 1; off < 256; off <<= 1) {
        const int u = (t >= off) ? sm[t - off] : 0;
        __syncthreads();
        sm[t] += u;
        __syncthreads();
    }
    int pre = partials[b] + (t ? sm[t - 1] : 0);
    if (base + 0 < n) rowptr[base + 0] = pre;
    if (base + 1 < n) rowptr[base + 1] = pre + e0;
    if (base + 2 < n) rowptr[base + 2] = pre + e0 + e1;
    if (base + 3 < n) rowptr[base + 3] = pre + e0 + e1 + e2;
}

// After this kernel rowptr[n] = end-of-segment(n).
__global__ __launch_bounds__(256) void csr_scatter(
    const int* __restrict__ src, const int* __restrict__ dst,
    const int* __restrict__ et, int* __restrict__ cursor /* = rowptr */,
    unsigned* __restrict__ packed, int nE)
{
    const int e = blockIdx.x * 256 + threadIdx.x;
    if (e < nE) {
        const int p = atomicAdd(&cursor[dst[e]], 1);
        packed[p] = ((unsigned)src[e] << 6) | (unsigned)et[e];   // R=50 < 64
    }
}

// ---------------- edge aggregation: one wave per dst node ------------------
template<int ACT>   // 0 = tanh, 1 = relu
__global__ __launch_bounds__(256) void rgcn_agg(
    const float* __restrict__ hb,       // [N][128]
    const float* __restrict__ comp,     // [R][2]
    const int* __restrict__ rowptr,     // rowptr[n] = end(n)
    const unsigned* __restrict__ packed,// [E] (src<<6 | et), grouped by dst
    float* __restrict__ io,             // in: self+bias, out: act(self+agg)
    int nNodes)
{
    const int lane = threadIdx.x & 63;
    const int w  = (blockIdx.x * 256 + threadIdx.x) >> 6;
    const int nW = (gridDim.x * 256) >> 6;
    const float2* __restrict__ comp2 = reinterpret_cast<const float2*>(comp);
    for (int n = w; n < nNodes; n += nW) {
        const int end = rowptr[n];
        const int beg = (n == 0) ? 0 : rowptr[n - 1];
        float acc0 = 0.f, acc1 = 0.f;
        for (int base = beg; base < end; base += 64) {
            const int cnt = min(64, end - base);
            int sp = 0; float c0 = 0.f, c1 = 0.f;
            if (lane < cnt) {
                const unsigned p = packed[base + lane];
                sp = (int)(p >> 6);
                const float2 cc = comp2[p & 63u];
                c0 = cc.x; c1 = cc.y;
            }
            int i = 0;
            for (; i + 4 <= cnt; i += 4) {
                const int   sA = __shfl(sp, i),     sB = __shfl(sp, i + 1);
                const int   sC = __shfl(sp, i + 2), sD = __shfl(sp, i + 3);
                const float a0 = __shfl(c0, i),     a1 = __shfl(c1, i);
                const float b0 = __shfl(c0, i + 1), b1 = __shfl(c1, i + 1);
                const float d0 = __shfl(c0, i + 2), d1 = __shfl(c1, i + 2);
                const float e0 = __shfl(c0, i + 3), e1 = __shfl(c1, i + 3);
                const float* __restrict__ rA = hb + (size_t)sA * 128;
                const float* __restrict__ rB = hb + (size_t)sB * 128;
                const float* __restrict__ rC = hb + (size_t)sC * 128;
                const float* __restrict__ rD = hb + (size_t)sD * 128;
                const float vA0 = rA[lane], vA1 = rA[64 + lane];
                const float vB0 = rB[lane], vB1 = rB[64 + lane];
                const float vC0 = rC[lane], vC1 = rC[64 + lane];
                const float vD0 = rD[lane], vD1 = rD[64 + lane];
                acc0 += a0 * vA0 + a1 * vA1 + b0 * vB0 + b1 * vB1;
                acc1 += d0 * vC0 + d1 * vC1 + e0 * vD0 + e1 * vD1;
            }
            for (; i < cnt; ++i) {
                const int   sA = __shfl(sp, i);
                const float a0 = __shfl(c0, i), a1 = __shfl(c1, i);
                const float* __restrict__ rA = hb + (size_t)sA * 128;
                acc0 += a0 * rA[lane] + a1 * rA[64 + lane];
            }
        }
        const float self = io[(size_t)n * 64 + lane];
        float o = self + acc0 + acc1;
        o = (ACT == 0) ? tanhf(o) : fmaxf(o, 0.f);
        io[(size_t)n * 64 + lane] = o;
    }
}

// ---------------------------------------------------------------------------
extern "C" void kernel_launch(void* const* d_in, const int* in_sizes, int n_in,
                              void* d_out, int out_size, void* d_ws, size_t ws_size,
                              hipStream_t stream)
{
    const float* node_emb = (const float*)d_in[0];   // [N][128]
    const float* basis1   = (const float*)d_in[1];   // [2][128][64]
    const float* comp1    = (const float*)d_in[2];   // [R][2]
    const float* loop_w1  = (const float*)d_in[3];   // [128][64]
    const float* bias1    = (const float*)d_in[4];   // [64]
    const float* basis2   = (const float*)d_in[5];   // [2][64][64]
    const float* comp2    = (const float*)d_in[6];   // [R][2]
    const float* loop_w2  = (const float*)d_in[7];   // [64][64]
    const float* bias2    = (const float*)d_in[8];   // [64]
    const int*   src      = (const int*)d_in[9];     // [E]
    const int*   dst      = (const int*)d_in[10];    // [E]
    const int*   et       = (const int*)d_in[11];    // [E]

    const int N = in_sizes[0] / 128;
    const int E = in_sizes[9];

    float* out = (float*)d_out;                      // [N][64]

    // workspace layout (all 16B-aligned)
    float*    hb       = (float*)d_ws;               // N*128 f
    float*    h        = hb + (size_t)N * 128;       // N*64 f
    unsigned* packed   = (unsigned*)(h + (size_t)N * 64); // E u32
    int*      deg      = (int*)(packed + E);         // N
    int*      rowptr   = deg + N;                    // N
    int*      partials = rowptr + N;                 // 256
    u16*      wt1h     = (u16*)(partials + 256);     // 192*128
    u16*      wt1l     = wt1h + 192 * 128;
    u16*      wt2h     = wt1l + 192 * 128;           // 192*64
    u16*      wt2l     = wt2h + 192 * 64;

    const int nBlkDense = (N + 127) / 128;
    const int nBlkE     = (E + 255) / 256;
    const int nC        = (N + 1023) / 1024;         // scan chunks (<=256)
    const int nBlkAgg   = (N + 3) / 4;               // 1 wave per node

    // ---- W pre-convert (bf16 hi/lo, transposed) ----
    wconv<<<96, 256, 0, stream>>>(loop_w1, basis1, loop_w2, basis2,
                                  wt1h, wt1l, wt2h, wt2l);

    // ---- CSR build (shared by both layers) ----
    hipMemsetAsync(deg, 0, (size_t)N * sizeof(int), stream);
    csr_hist      <<<nBlkE, 256, 0, stream>>>(dst, deg, E);
    csr_reduce    <<<nC,    256, 0, stream>>>(deg, partials, N);
    csr_scan_part <<<1,     256, 0, stream>>>(partials, nC);
    csr_scan_final<<<nC,    256, 0, stream>>>(deg, partials, rowptr, N);
    csr_scatter   <<<nBlkE, 256, 0, stream>>>(src, dst, et, rowptr, packed, E);

    // ---- layer 1 ----
    rgcn_dense_mfma<128><<<nBlkDense, 512, 0, stream>>>(
        node_emb, wt1h, wt1l, bias1, h, hb, N);
    rgcn_agg<0><<<nBlkAgg, 256, 0, stream>>>(hb, comp1, rowptr, packed, h, N);

    // ---- layer 2 ----
    rgcn_dense_mfma<64><<<nBlkDense, 512, 0, stream>>>(
        h, wt2h, wt2l, bias2, out, hb, N);
    rgcn_agg<1><<<nBlkAgg, 256, 0, stream>>>(hb, comp2, rowptr, packed, out, N);
}